// Round 1
// baseline (64.029 us; speedup 1.0000x reference)
//
#include <hip/hip_runtime.h>
#include <math.h>

// Multitask loss:
//   loss = mean(bce(pb, tb))                       [B]
//        + mean(bce(pt, tt))                       [B,5]  (mean over 5B elems)
//        + mean(-log_softmax(ps)[i, ts[i]])        [B,16]
//        + mean((pb>0) ^ (pt[:,0]>0))
//        + mean((pb>0) ^ (argmax(ps)>0))
// bce(x,y) = max(x,0) - x*y + log1p(exp(-|x|))

#define NBLOCKS 2048
#define NTHREADS 256

__device__ __forceinline__ float bce_term(float x, float y) {
    return fmaxf(x, 0.0f) - x * y + log1pf(expf(-fabsf(x)));
}

__global__ __launch_bounds__(NTHREADS) void mtl_partial_kernel(
    const float* __restrict__ pb,   // [B]    y_pred_binary
    const float* __restrict__ pt,   // [B,5]  y_pred_type
    const float* __restrict__ ps,   // [B,16] y_pred_source
    const float* __restrict__ tb,   // [B]    y_true_binary
    const float* __restrict__ tt,   // [B,5]  y_true_type
    const int*   __restrict__ ts,   // [B]    y_true_source
    double* __restrict__ partial,   // [NBLOCKS]
    int B)
{
    double acc = 0.0;
    const int stride = gridDim.x * blockDim.x;
    for (int i = blockIdx.x * blockDim.x + threadIdx.x; i < B; i += stride) {
        // ---- task A: binary BCE ----
        const float xb = pb[i];
        const float yb = tb[i];
        float c = bce_term(xb, yb);

        // ---- task B: type BCE (5 elems/row, mean over 5B -> weight 0.2) ----
        float t0 = 0.0f;
        float st = 0.0f;
        const size_t base5 = (size_t)i * 5;
        #pragma unroll
        for (int j = 0; j < 5; ++j) {
            const float x = pt[base5 + j];
            const float y = tt[base5 + j];
            if (j == 0) t0 = x;
            st += bce_term(x, y);
        }
        c += st * 0.2f;

        // ---- task C: 16-way CE over log_softmax ----
        float xs[16];
        const float4* ps4 = reinterpret_cast<const float4*>(ps + (size_t)i * 16);
        #pragma unroll
        for (int q = 0; q < 4; ++q) {
            const float4 v = ps4[q];
            xs[q * 4 + 0] = v.x;
            xs[q * 4 + 1] = v.y;
            xs[q * 4 + 2] = v.z;
            xs[q * 4 + 3] = v.w;
        }
        float m = xs[0];
        int am = 0;  // argmax, first occurrence on ties (strict >)
        #pragma unroll
        for (int j = 1; j < 16; ++j) {
            if (xs[j] > m) { m = xs[j]; am = j; }
        }
        float se = 0.0f;
        #pragma unroll
        for (int j = 0; j < 16; ++j) se += expf(xs[j] - m);
        const int t = ts[i];
        c += m + logf(se) - xs[t];   // -logp[t]

        // ---- consistency XOR terms ----
        const bool bc = xb > 0.0f;
        const bool tc = t0 > 0.0f;
        const bool sc = am > 0;
        c += (bc != tc) ? 1.0f : 0.0f;
        c += (bc != sc) ? 1.0f : 0.0f;

        acc += (double)c;
    }

    // ---- block reduction (wave shfl, then cross-wave via LDS) ----
    #pragma unroll
    for (int off = 32; off > 0; off >>= 1)
        acc += __shfl_down(acc, off, 64);

    __shared__ double smem[NTHREADS / 64];
    const int lane = threadIdx.x & 63;
    const int wave = threadIdx.x >> 6;
    if (lane == 0) smem[wave] = acc;
    __syncthreads();
    if (threadIdx.x == 0) {
        double s = 0.0;
        #pragma unroll
        for (int w = 0; w < NTHREADS / 64; ++w) s += smem[w];
        partial[blockIdx.x] = s;
    }
}

__global__ __launch_bounds__(NTHREADS) void mtl_final_kernel(
    const double* __restrict__ partial, float* __restrict__ out, int nblocks, int B)
{
    double acc = 0.0;
    for (int i = threadIdx.x; i < nblocks; i += NTHREADS)
        acc += partial[i];
    #pragma unroll
    for (int off = 32; off > 0; off >>= 1)
        acc += __shfl_down(acc, off, 64);
    __shared__ double smem[NTHREADS / 64];
    const int lane = threadIdx.x & 63;
    const int wave = threadIdx.x >> 6;
    if (lane == 0) smem[wave] = acc;
    __syncthreads();
    if (threadIdx.x == 0) {
        double s = 0.0;
        #pragma unroll
        for (int w = 0; w < NTHREADS / 64; ++w) s += smem[w];
        out[0] = (float)(s / (double)B);
    }
}

extern "C" void kernel_launch(void* const* d_in, const int* in_sizes, int n_in,
                              void* d_out, int out_size, void* d_ws, size_t ws_size,
                              hipStream_t stream) {
    const float* pb = (const float*)d_in[0];
    const float* pt = (const float*)d_in[1];
    const float* ps = (const float*)d_in[2];
    const float* tb = (const float*)d_in[3];
    const float* tt = (const float*)d_in[4];
    const int*   ts = (const int*)d_in[5];
    float* out = (float*)d_out;
    const int B = in_sizes[0];

    double* partial = (double*)d_ws;  // NBLOCKS doubles = 16 KiB

    mtl_partial_kernel<<<NBLOCKS, NTHREADS, 0, stream>>>(pb, pt, ps, tb, tt, ts, partial, B);
    mtl_final_kernel<<<1, NTHREADS, 0, stream>>>(partial, out, NBLOCKS, B);
}

// Round 2
// 44.648 us; speedup vs baseline: 1.4341x; 1.4341x over previous
//
#include <hip/hip_runtime.h>
#include <math.h>

// Multitask loss (fused single pass):
//   loss = mean(bce(pb, tb))                       [B]
//        + mean(bce(pt, tt))                       [B,5]  (mean over 5B elems)
//        + mean(-log_softmax(ps)[i, ts[i]])        [B,16]
//        + mean((pb>0) ^ (pt[:,0]>0))
//        + mean((pb>0) ^ (argmax(ps)>0))
// bce(x,y) = max(x,0) - x*y + log1p(exp(-|x|))
//
// All transcendentals via fast intrinsics (__expf/__logf -> v_exp_f32/v_log_f32):
// tolerance is 0.117 absmax on a ~5.8 scalar, so ~1e-6 relative error is fine.

#define NBLOCKS 2048
#define NTHREADS 256

__device__ __forceinline__ float softplus_neg_abs(float x) {
    // log1p(exp(-|x|)); log argument is in (1, 2] so plain __logf is safe
    // (no cancellation; absolute error ~1e-7).
    return __logf(1.0f + __expf(-fabsf(x)));
}

__global__ __launch_bounds__(NTHREADS) void mtl_partial_kernel(
    const float* __restrict__ pb,   // [B]    y_pred_binary
    const float* __restrict__ pt,   // [B,5]  y_pred_type
    const float* __restrict__ ps,   // [B,16] y_pred_source
    const float* __restrict__ tb,   // [B]    y_true_binary
    const float* __restrict__ tt,   // [B,5]  y_true_type
    const int*   __restrict__ ts,   // [B]    y_true_source
    double* __restrict__ partial,   // [NBLOCKS]
    int B)
{
    float accf = 0.0f;  // <= ~8 rows/thread, each ~6: f32 exact enough
    const int stride = gridDim.x * blockDim.x;
    for (int i = blockIdx.x * blockDim.x + threadIdx.x; i < B; i += stride) {
        // ---- task A: binary BCE ----
        const float xb = pb[i];
        const float yb = tb[i];
        const int   t  = ts[i];
        float c = fmaxf(xb, 0.0f) - xb * yb + softplus_neg_abs(xb);

        // ---- task B: type BCE (5 elems/row, weight 1/5) ----
        const float* ptr = pt + (size_t)i * 5;
        const float* ttr = tt + (size_t)i * 5;
        float t0 = 0.0f;
        float st = 0.0f;
        #pragma unroll
        for (int j = 0; j < 5; ++j) {
            const float x = ptr[j];
            const float y = ttr[j];
            if (j == 0) t0 = x;
            st += fmaxf(x, 0.0f) - x * y + softplus_neg_abs(x);
        }
        c += st * 0.2f;

        // ---- task C: 16-way CE over log_softmax ----
        float xs[16];  // static indexing only -> stays in VGPRs
        const float4* ps4 = reinterpret_cast<const float4*>(ps + (size_t)i * 16);
        #pragma unroll
        for (int q = 0; q < 4; ++q) {
            const float4 v = ps4[q];
            xs[q * 4 + 0] = v.x;
            xs[q * 4 + 1] = v.y;
            xs[q * 4 + 2] = v.z;
            xs[q * 4 + 3] = v.w;
        }
        // max of xs[1..15]; argmax>0  <=>  m15 > xs[0] (strict, matches
        // first-occurrence tie-break of jnp.argmax)
        float m15 = xs[1];
        #pragma unroll
        for (int j = 2; j < 16; ++j) m15 = fmaxf(m15, xs[j]);
        const float m = fmaxf(xs[0], m15);

        float se = 0.0f;
        float xt = 0.0f;  // xs[t] selected via unrolled cndmask (no scratch)
        #pragma unroll
        for (int j = 0; j < 16; ++j) {
            se += __expf(xs[j] - m);
            xt = (j == t) ? xs[j] : xt;
        }
        c += m + __logf(se) - xt;  // -logp[t]

        // ---- consistency XOR terms ----
        const bool bc = xb > 0.0f;
        const bool tc = t0 > 0.0f;
        const bool sc = m15 > xs[0];
        c += (bc != tc) ? 1.0f : 0.0f;
        c += (bc != sc) ? 1.0f : 0.0f;

        accf += c;
    }

    // ---- block reduction (wave shfl in f32, then cross-wave via LDS) ----
    float a = accf;
    #pragma unroll
    for (int off = 32; off > 0; off >>= 1)
        a += __shfl_down(a, off, 64);

    __shared__ double smem[NTHREADS / 64];
    const int lane = threadIdx.x & 63;
    const int wave = threadIdx.x >> 6;
    if (lane == 0) smem[wave] = (double)a;
    __syncthreads();
    if (threadIdx.x == 0) {
        double s = 0.0;
        #pragma unroll
        for (int w = 0; w < NTHREADS / 64; ++w) s += smem[w];
        partial[blockIdx.x] = s;
    }
}

__global__ __launch_bounds__(NTHREADS) void mtl_final_kernel(
    const double* __restrict__ partial, float* __restrict__ out, int nblocks, int B)
{
    double acc = 0.0;
    for (int i = threadIdx.x; i < nblocks; i += NTHREADS)
        acc += partial[i];
    #pragma unroll
    for (int off = 32; off > 0; off >>= 1)
        acc += __shfl_down(acc, off, 64);
    __shared__ double smem[NTHREADS / 64];
    const int lane = threadIdx.x & 63;
    const int wave = threadIdx.x >> 6;
    if (lane == 0) smem[wave] = acc;
    __syncthreads();
    if (threadIdx.x == 0) {
        double s = 0.0;
        #pragma unroll
        for (int w = 0; w < NTHREADS / 64; ++w) s += smem[w];
        out[0] = (float)(s / (double)B);
    }
}

extern "C" void kernel_launch(void* const* d_in, const int* in_sizes, int n_in,
                              void* d_out, int out_size, void* d_ws, size_t ws_size,
                              hipStream_t stream) {
    const float* pb = (const float*)d_in[0];
    const float* pt = (const float*)d_in[1];
    const float* ps = (const float*)d_in[2];
    const float* tb = (const float*)d_in[3];
    const float* tt = (const float*)d_in[4];
    const int*   ts = (const int*)d_in[5];
    float* out = (float*)d_out;
    const int B = in_sizes[0];

    double* partial = (double*)d_ws;  // NBLOCKS doubles = 16 KiB

    mtl_partial_kernel<<<NBLOCKS, NTHREADS, 0, stream>>>(pb, pt, ps, tb, tt, ts, partial, B);
    mtl_final_kernel<<<1, NTHREADS, 0, stream>>>(partial, out, NBLOCKS, B);
}